// Round 10
// baseline (1512.045 us; speedup 1.0000x reference)
//
#include <hip/hip_runtime.h>

// DRL4SSP pointer-network decoder, MI355X (gfx950).
// 64 batches -> 64 blocks x 512 threads, 127 sequential steps.
// base1/base2/Wcomb/static in LDS. All weight streams (Whh, w1h, w2d,
// static_h) read per-thread-contiguous from L2 as dwordx4, software-pipelined
// ONE PHASE AHEAD across lgkmcnt-only barriers (raw s_barrier, no vmcnt(0)
// drain) so L2 latency never sits on the critical path.

namespace {

constexpr int kB = 64, kSS = 8, kDS = 4, kH = 128, kS = 128, kT = 127, kG3 = 384;

// workspace layout (float offsets)
constexpr size_t OFF_BASE1 = 0;
constexpr size_t OFF_BASE2 = OFF_BASE1 + (size_t)kB * kH * kS;
constexpr size_t OFF_SHG   = OFF_BASE2 + (size_t)kB * kH * kS;   // static_h [b][h][s]
constexpr size_t OFF_DHG   = OFF_SHG   + (size_t)kB * kH * kS;
constexpr size_t OFF_WCT   = OFF_DHG   + (size_t)kB * kH * kS;   // WcombT [8][384]
constexpr size_t OFF_BCOMB = OFF_WCT   + (size_t)kSS * kG3;

// dynamic-LDS layout (float offsets)
constexpr int L_BASE1 = 0;        // 16384
constexpr int L_BASE2 = 16384;    // 16384
constexpr int L_WCT   = 32768;    // 3072
constexpr int L_BC    = 35840;    // 384
constexpr int L_BH    = 36224;    // 384
constexpr int L_STAT  = 36608;    // 1024
constexpr int L_PG    = 37632;    // 1536  [seg][gate][128]
constexpr int L_PU    = 39168;    // 512
constexpr int L_PA    = 39680;    // 512
constexpr int L_MASK  = 40192;    // 128
constexpr int L_DEC   = 40320;    // 8
constexpr int L_WSUM  = 40328;    // 4
constexpr int L_RINV  = 40332;    // 1
constexpr int LDS_FLOATS = 40336;
constexpr int LDS_BYTES  = LDS_FLOATS * 4;  // 161,344 <= 163,840

__device__ __forceinline__ float rlane(float v, int l) {
  return __uint_as_float(__builtin_amdgcn_readlane(__float_as_uint(v), (unsigned)l));
}

__device__ __forceinline__ float tanh_fast(float x) {
  // identical to the round-1..9 (passing) formula — trajectory-sensitive
  x = fminf(15.f, fmaxf(-15.f, x));
  float e = __expf(-2.f * x);
  return (1.f - e) * __builtin_amdgcn_rcpf(1.f + e);
}

// LDS-only barrier: drain DS ops, do NOT drain vmcnt — in-flight global
// (read-only weight prefetch) loads ride across.
__device__ __forceinline__ void lds_barrier() {
  asm volatile("s_waitcnt lgkmcnt(0)" ::: "memory");
  __builtin_amdgcn_s_barrier();
}

// 8 fmas into acc: acc += rlane(v, base+j) * buf[j], buf = two float4s.
#define ACC8(acc, v, f40, f41, base)                    \
  acc = fmaf(rlane(v, (base) + 0), (f40).x, acc);       \
  acc = fmaf(rlane(v, (base) + 1), (f40).y, acc);       \
  acc = fmaf(rlane(v, (base) + 2), (f40).z, acc);       \
  acc = fmaf(rlane(v, (base) + 3), (f40).w, acc);       \
  acc = fmaf(rlane(v, (base) + 4), (f41).x, acc);       \
  acc = fmaf(rlane(v, (base) + 5), (f41).y, acc);       \
  acc = fmaf(rlane(v, (base) + 6), (f41).z, acc);       \
  acc = fmaf(rlane(v, (base) + 7), (f41).w, acc);

// ---------------- precompute kernels ----------------

__global__ void prep_w(const float* __restrict__ W_ih, const float* __restrict__ W_dec,
                       const float* __restrict__ b_ih, const float* __restrict__ b_dec,
                       float* __restrict__ ws) {
  const int tid = threadIdx.x;
  float* WcT   = ws + OFF_WCT;    // [i][j] = sum_k W_ih[j,k] W_dec[k,i]
  float* bcomb = ws + OFF_BCOMB;
  for (int idx = tid; idx < kSS * kG3; idx += 256) {
    int i = idx / kG3, j = idx % kG3;
    float acc = 0.f;
    for (int k = 0; k < kH; ++k) acc = fmaf(W_ih[j * kH + k], W_dec[k * kSS + i], acc);
    WcT[idx] = acc;
  }
  for (int j = tid; j < kG3; j += 256) {
    float acc = b_ih[j];
    for (int k = 0; k < kH; ++k) acc = fmaf(W_ih[j * kH + k], b_dec[k], acc);
    bcomb[j] = acc;
  }
}

__global__ void prep_sh(const float* __restrict__ stat_g, const float* __restrict__ dyn_g,
                        const float* __restrict__ W_s, const float* __restrict__ b_s,
                        const float* __restrict__ W_d, const float* __restrict__ b_d,
                        float* __restrict__ ws) {
  const int b = blockIdx.x, tid = threadIdx.x;
  float* sh_g = ws + OFF_SHG;
  float* dh_g = ws + OFF_DHG;
  const float* sb = stat_g + (size_t)b * kSS * kS;
  const float* db = dyn_g + (size_t)b * kDS * kS;
  for (int idx = tid; idx < kH * kS; idx += 256) {
    int k = idx >> 7, s = idx & 127;
    float acc = b_s[k];
#pragma unroll
    for (int i = 0; i < kSS; ++i) acc = fmaf(W_s[k * kSS + i], sb[i * kS + s], acc);
    sh_g[(size_t)b * kH * kS + idx] = acc;
    float accd = b_d[k];
#pragma unroll
    for (int i = 0; i < kDS; ++i) accd = fmaf(W_d[k * kDS + i], db[i * kS + s], accd);
    dh_g[(size_t)b * kH * kS + idx] = accd;
  }
}

__global__ void prep_base(const float* __restrict__ ww1, const float* __restrict__ ww2,
                          float* __restrict__ ws) {
  const int b = blockIdx.x, which = blockIdx.y, tid = threadIdx.x;
  const float* sh_g = ws + OFF_SHG + (size_t)b * kH * kS;
  const float* dh_g = ws + OFF_DHG + (size_t)b * kH * kS;
  const float* ww = which ? ww2 : ww1;
  const int dh_off = which ? 2 * kH : kH;
  float* dst = ws + (which ? OFF_BASE2 : OFF_BASE1) + (size_t)b * kH * kS;
  for (int idx = tid; idx < kH * kS / 4; idx += 256) {
    int h = idx >> 5, sq = idx & 31;
    const float* wrow = ww + h * kG3;
    float4 acc = make_float4(0.f, 0.f, 0.f, 0.f);
#pragma unroll 8
    for (int k = 0; k < kH; ++k) {
      float w = wrow[k];
      float4 v = *reinterpret_cast<const float4*>(sh_g + k * kS + sq * 4);
      acc.x = fmaf(w, v.x, acc.x); acc.y = fmaf(w, v.y, acc.y);
      acc.z = fmaf(w, v.z, acc.z); acc.w = fmaf(w, v.w, acc.w);
    }
#pragma unroll 8
    for (int k = 0; k < kH; ++k) {
      float w = wrow[dh_off + k];
      float4 v = *reinterpret_cast<const float4*>(dh_g + k * kS + sq * 4);
      acc.x = fmaf(w, v.x, acc.x); acc.y = fmaf(w, v.y, acc.y);
      acc.z = fmaf(w, v.z, acc.z); acc.w = fmaf(w, v.w, acc.w);
    }
    *reinterpret_cast<float4*>(dst + h * kS + sq * 4) = acc;
  }
}

// ---------------- main sequential kernel ----------------

__global__ __launch_bounds__(512, 2) void ptrnet_main(
    const float* __restrict__ stat_g, const float* __restrict__ dyn_g,
    const float* __restrict__ vv1_g, const float* __restrict__ vv2_g,
    const float* __restrict__ bhh_g, const float* __restrict__ Whh_g,
    const float* __restrict__ ww1_g, const float* __restrict__ ww2_g,
    const float* __restrict__ ws, float* __restrict__ out) {
  extern __shared__ float sm[];
  const int b = blockIdx.x;
  const int tid = threadIdx.x;
  const int hh = tid & 127;          // output/s index
  const int seg = tid >> 7;          // 0..3: 32-wide k/h chunk
  const int lane = tid & 63;
  const int li = seg * 32 + (hh & 31);  // this thread's "owned" 128-index

  float* base1_l = sm + L_BASE1;
  float* base2_l = sm + L_BASE2;
  float* wct_l   = sm + L_WCT;
  float* bc_l    = sm + L_BC;
  float* bh_l    = sm + L_BH;
  float* stat_l  = sm + L_STAT;
  float* pg_l    = sm + L_PG;
  float* pu_l    = sm + L_PU;
  float* pa_l    = sm + L_PA;
  float* mask_l  = sm + L_MASK;
  float* dec_l   = sm + L_DEC;
  float* wsum_l  = sm + L_WSUM;
  float* rinv_l  = sm + L_RINV;

  // ---- LDS init (one-time) ----
  {
    const float4* b1g = reinterpret_cast<const float4*>(ws + OFF_BASE1 + (size_t)b * kH * kS);
    const float4* b2g = reinterpret_cast<const float4*>(ws + OFF_BASE2 + (size_t)b * kH * kS);
    float4* b1l = reinterpret_cast<float4*>(base1_l);
    float4* b2l = reinterpret_cast<float4*>(base2_l);
    for (int i = tid; i < kH * kS / 4; i += 512) { b1l[i] = b1g[i]; b2l[i] = b2g[i]; }
    for (int i = tid; i < kSS * kG3; i += 512) wct_l[i] = ws[OFF_WCT + i];
    if (tid < kG3) { bc_l[tid] = ws[OFF_BCOMB + tid]; bh_l[tid] = bhh_g[tid]; }
    for (int i = tid; i < kSS * kS; i += 512) stat_l[i] = stat_g[(size_t)b * kSS * kS + i];
    if (tid < kS)
      mask_l[tid] = (tid == 0 || dyn_g[(size_t)b * kDS * kS + tid] != 0.f) ? 0.f : 1.f;
    if (tid < kSS) dec_l[tid] = 0.f;
  }

  float v_vv1 = vv1_g[li], v_vv2 = vv2_g[li];
  float h_prev = 0.f;

  // per-thread contiguous weight rows (all dwordx4-aligned)
  const float* whpr = Whh_g + (size_t)(0 * kH + hh) * kH + seg * 32;  // gate r
  const float* whpz = whpr + (size_t)kH * kH;                         // gate z
  const float* whpn = whpz + (size_t)kH * kH;                         // gate n
  const float* w1row = ww1_g + (size_t)hh * kG3 + 2 * kH + seg * 32;  // w1h[hh][seg*32..]
  const float* w2row = ww2_g + (size_t)hh * kG3 + kH + seg * 32;      // w2d[hh][seg*32..]
  const float* shrow = ws + OFF_SHG + (size_t)b * kH * kS + (size_t)hh * kS + seg * 32;
  __syncthreads();

  // prologue: prefetch gates r,z for the first iteration
  float4 qr[8], qz[8];
#pragma unroll
  for (int j = 0; j < 8; ++j) qr[j] = *reinterpret_cast<const float4*>(whpr + 4 * j);
#pragma unroll
  for (int j = 0; j < 8; ++j) qz[j] = *reinterpret_cast<const float4*>(whpz + 4 * j);

  for (int t = 0; t < kT; ++t) {
    float4 w1b[8], shb[8], w2b[8];

    // ---- PH_A: gi (own li) + gh partials (Whh r/z prefetched, n in-phase) ----
    float gi0, gi1, gi2;
    {
      float v_dec = dec_l[lane & 7];
      gi0 = bc_l[li]; gi1 = bc_l[kH + li]; gi2 = bc_l[2 * kH + li];
#pragma unroll
      for (int i = 0; i < 8; ++i) {
        float d = rlane(v_dec, i);
        gi0 = fmaf(wct_l[i * kG3 + li], d, gi0);
        gi1 = fmaf(wct_l[i * kG3 + kH + li], d, gi1);
        gi2 = fmaf(wct_l[i * kG3 + 2 * kH + li], d, gi2);
      }
      // issue gate n loads now; cover latency with the r/z fma block below
      float4 qn[8];
#pragma unroll
      for (int j = 0; j < 8; ++j) qn[j] = *reinterpret_cast<const float4*>(whpn + 4 * j);
      float a0 = 0.f, a1 = 0.f;
#pragma unroll
      for (int j = 0; j < 8; ++j) {
        float4 w0 = qr[j], w1 = qz[j];
        float h0 = rlane(h_prev, 4 * j + 0), h1 = rlane(h_prev, 4 * j + 1);
        float h2 = rlane(h_prev, 4 * j + 2), h3 = rlane(h_prev, 4 * j + 3);
        a0 = fmaf(h0, w0.x, a0); a1 = fmaf(h0, w1.x, a1);
        a0 = fmaf(h1, w0.y, a0); a1 = fmaf(h1, w1.y, a1);
        a0 = fmaf(h2, w0.z, a0); a1 = fmaf(h2, w1.z, a1);
        a0 = fmaf(h3, w0.w, a0); a1 = fmaf(h3, w1.w, a1);
      }
      // issue w1 prefetch for PH_B (consumed after next barrier)
#pragma unroll
      for (int j = 0; j < 8; ++j) w1b[j] = *reinterpret_cast<const float4*>(w1row + 4 * j);
      float a2x = 0.f, a2y = 0.f;
#pragma unroll
      for (int j = 0; j < 8; ++j) {
        float4 w = qn[j];
        a2x = fmaf(rlane(h_prev, 4 * j + 0), w.x, a2x);
        a2y = fmaf(rlane(h_prev, 4 * j + 1), w.y, a2y);
        a2x = fmaf(rlane(h_prev, 4 * j + 2), w.z, a2x);
        a2y = fmaf(rlane(h_prev, 4 * j + 3), w.w, a2y);
      }
      pg_l[(seg * 3 + 0) * kS + hh] = a0;
      pg_l[(seg * 3 + 1) * kS + hh] = a1;
      pg_l[(seg * 3 + 2) * kS + hh] = a2x + a2y;
    }
    lds_barrier();

    // ---- PH_B: GRU (replicated per-thread) + u1 (w1b prefetched) ----
    {
      float gh0 = bh_l[li] +
          ((pg_l[(0*3+0)*kS+li] + pg_l[(1*3+0)*kS+li]) + (pg_l[(2*3+0)*kS+li] + pg_l[(3*3+0)*kS+li]));
      float gh1 = bh_l[kH + li] +
          ((pg_l[(0*3+1)*kS+li] + pg_l[(1*3+1)*kS+li]) + (pg_l[(2*3+1)*kS+li] + pg_l[(3*3+1)*kS+li]));
      float gh2 = bh_l[2*kH + li] +
          ((pg_l[(0*3+2)*kS+li] + pg_l[(1*3+2)*kS+li]) + (pg_l[(2*3+2)*kS+li] + pg_l[(3*3+2)*kS+li]));
      float r = 1.f / (1.f + __expf(-(gi0 + gh0)));
      float z = 1.f / (1.f + __expf(-(gi1 + gh1)));
      float x = gi2 + r * gh2;
      x = fminf(15.f, fmaxf(-15.f, x));
      float e = __expf(-2.f * x);
      float n = (1.f - e) / (1.f + e);
      float hnew = (1.f - z) * n + z * h_prev;
      h_prev = hnew;
      float acc0 = 0.f, acc1 = 0.f;
      ACC8(acc0, hnew, w1b[0], w1b[1], 0);
      ACC8(acc1, hnew, w1b[2], w1b[3], 8);
      ACC8(acc0, hnew, w1b[4], w1b[5], 16);
      ACC8(acc1, hnew, w1b[6], w1b[7], 24);
      pu_l[seg * kS + hh] = acc0 + acc1;
    }
    lds_barrier();

    // ---- PH_C: attn1 partials (tanh, base1 in LDS); prefetch sh for PH_E ----
    {
#pragma unroll
      for (int j = 0; j < 8; ++j) shb[j] = *reinterpret_cast<const float4*>(shrow + 4 * j);
      float v_u1 = (pu_l[li] + pu_l[kS + li]) + (pu_l[2*kS + li] + pu_l[3*kS + li]);
      float acc0 = 0.f, acc1 = 0.f;
#pragma unroll
      for (int kk = 0; kk < 16; ++kk) {
        float xa = base1_l[(seg * 32 + 2*kk) * kS + hh] + rlane(v_u1, 2*kk);
        float xb = base1_l[(seg * 32 + 2*kk+1) * kS + hh] + rlane(v_u1, 2*kk+1);
        acc0 = fmaf(rlane(v_vv1, 2*kk), tanh_fast(xa), acc0);
        acc1 = fmaf(rlane(v_vv1, 2*kk+1), tanh_fast(xb), acc1);
      }
      pa_l[seg * kS + hh] = acc0 + acc1;
    }
    lds_barrier();

    // ---- PH_E: softmax1 exp + chunk sums + dytext (shb prefetched); prefetch w2 ----
    {
#pragma unroll
      for (int j = 0; j < 8; ++j) w2b[j] = *reinterpret_cast<const float4*>(w2row + 4 * j);
      float a = (pa_l[li] + pa_l[kS + li]) + (pa_l[2*kS + li] + pa_l[3*kS + li]);
      float ee = __expf(fminf(a, 60.f));
      float ssum = ee;
#pragma unroll
      for (int off = 1; off < 32; off <<= 1) ssum += __shfl_xor(ssum, off);
      if ((lane & 31) == 0) wsum_l[seg] = ssum;
      float acc0 = 0.f, acc1 = 0.f;
      ACC8(acc0, ee, shb[0], shb[1], 0);
      ACC8(acc1, ee, shb[2], shb[3], 8);
      ACC8(acc0, ee, shb[4], shb[5], 16);
      ACC8(acc1, ee, shb[6], shb[7], 24);
      pu_l[seg * kS + hh] = acc0 + acc1;
    }
    lds_barrier();

    // ---- PH_F: u2 partials (w2b prefetched); one thread computes 1/sum ----
    {
      float v_dy = (pu_l[li] + pu_l[kS + li]) + (pu_l[2*kS + li] + pu_l[3*kS + li]);
      float acc0 = 0.f, acc1 = 0.f;
      ACC8(acc0, v_dy, w2b[0], w2b[1], 0);
      ACC8(acc1, v_dy, w2b[2], w2b[3], 8);
      ACC8(acc0, v_dy, w2b[4], w2b[5], 16);
      ACC8(acc1, v_dy, w2b[6], w2b[7], 24);
      pa_l[seg * kS + hh] = acc0 + acc1;
      if (tid == 0) rinv_l[0] = 1.0f / ((wsum_l[0] + wsum_l[1]) + (wsum_l[2] + wsum_l[3]));
    }
    lds_barrier();

    // ---- PH_G: attn2 partials (tanh, base2 in LDS); prefetch next iter's r,z ----
    {
#pragma unroll
      for (int j = 0; j < 8; ++j) qr[j] = *reinterpret_cast<const float4*>(whpr + 4 * j);
#pragma unroll
      for (int j = 0; j < 8; ++j) qz[j] = *reinterpret_cast<const float4*>(whpz + 4 * j);
      float rin = rinv_l[0];
      float v_u2 = ((pa_l[li] + pa_l[kS + li]) + (pa_l[2*kS + li] + pa_l[3*kS + li])) * rin;
      float acc0 = 0.f, acc1 = 0.f;
#pragma unroll
      for (int kk = 0; kk < 16; ++kk) {
        float xa = base2_l[(seg * 32 + 2*kk) * kS + hh] + rlane(v_u2, 2*kk);
        float xb = base2_l[(seg * 32 + 2*kk+1) * kS + hh] + rlane(v_u2, 2*kk+1);
        acc0 = fmaf(rlane(v_vv2, 2*kk), tanh_fast(xa), acc0);
        acc1 = fmaf(rlane(v_vv2, 2*kk+1), tanh_fast(xb), acc1);
      }
      pu_l[seg * kS + hh] = acc0 + acc1;
    }
    lds_barrier();

    // ---- PH_H: logits, argmax, logsumexp, state update (wave 0 only) ----
    if (tid < 64) {
      int s0 = lane, s1 = lane + 64;
      float l0 = (pu_l[s0] + pu_l[kS + s0]) + (pu_l[2*kS + s0] + pu_l[3*kS + s0]);
      float l1 = (pu_l[s1] + pu_l[kS + s1]) + (pu_l[2*kS + s1] + pu_l[3*kS + s1]);
      l0 += (mask_l[s0] > 0.f ? 0.f : -1e30f);
      l1 += (mask_l[s1] > 0.f ? 0.f : -1e30f);
      float es = __expf(l0) + __expf(l1);
      float mv; int mi;
      if (l1 > l0) { mv = l1; mi = s1; } else { mv = l0; mi = s0; }
#pragma unroll
      for (int off = 1; off < 64; off <<= 1) {
        float ov = __shfl_xor(mv, off);
        int oi = __shfl_xor(mi, off);
        if (ov > mv || (ov == mv && oi < mi)) { mv = ov; mi = oi; }
        es += __shfl_xor(es, off);
      }
      if (lane == 0) {
        out[b * kT + t] = (float)mi;
        out[kB * kT + b * kT + t] = mv - __logf(es);
        mask_l[mi] = 0.f;
      }
      if (lane < kSS) dec_l[lane] = stat_l[lane * kS + mi];
    }
    lds_barrier();
  }
}

}  // namespace

extern "C" void kernel_launch(void* const* d_in, const int* in_sizes, int n_in,
                              void* d_out, int out_size, void* d_ws, size_t ws_size,
                              hipStream_t stream) {
  const float* stat_g = (const float*)d_in[0];
  const float* dyn_g  = (const float*)d_in[1];
  const float* W_s   = (const float*)d_in[3];
  const float* b_s   = (const float*)d_in[4];
  const float* W_d   = (const float*)d_in[5];
  const float* b_d   = (const float*)d_in[6];
  const float* W_dec = (const float*)d_in[7];
  const float* b_dec = (const float*)d_in[8];
  const float* vv1   = (const float*)d_in[9];
  const float* ww1   = (const float*)d_in[10];
  const float* vv2   = (const float*)d_in[11];
  const float* ww2   = (const float*)d_in[12];
  const float* W_ih  = (const float*)d_in[13];
  const float* W_hh  = (const float*)d_in[14];
  const float* b_ih  = (const float*)d_in[15];
  const float* b_hh  = (const float*)d_in[16];

  float* ws = (float*)d_ws;
  float* out = (float*)d_out;

  hipFuncSetAttribute(reinterpret_cast<const void*>(ptrnet_main),
                      hipFuncAttributeMaxDynamicSharedMemorySize, LDS_BYTES);

  prep_w<<<1, 256, 0, stream>>>(W_ih, W_dec, b_ih, b_dec, ws);
  prep_sh<<<kB, 256, 0, stream>>>(stat_g, dyn_g, W_s, b_s, W_d, b_d, ws);
  prep_base<<<dim3(kB, 2), 256, 0, stream>>>(ww1, ww2, ws);
  ptrnet_main<<<kB, 512, LDS_BYTES, stream>>>(stat_g, dyn_g, vv1, vv2, b_hh, W_hh,
                                              ww1, ww2, ws, out);
}